// Round 2
// baseline (917.884 us; speedup 1.0000x reference)
//
#include <hip/hip_runtime.h>
#include <hip/hip_bf16.h>

typedef __attribute__((ext_vector_type(4))) int   int32x4;
typedef __attribute__((ext_vector_type(4))) float float4v;

// ---------------- stats layout (floats at ws+0) ----------------
// [0]=absmax_x [1]=absmax_w1 [2]=absmax_w2 [3]=absmax_w3 [4]=hmax1 [5]=hmax2

__global__ void init_stats(float* stats) {
    if (threadIdx.x < 64) stats[threadIdx.x] = 0.0f;
}

// ---------------- max|x| reduction ----------------
// 16 floats (4 independent float4 loads) per thread per iteration -> enough
// loads in flight to cover HBM latency (prev version: 1 load in flight, 554 GB/s).
__global__ void maxabs_kernel(const float* __restrict__ src, long n16, float* __restrict__ out) {
    long i = (long)blockIdx.x * blockDim.x + threadIdx.x;
    long stride = (long)gridDim.x * blockDim.x;
    float m0 = 0.0f, m1 = 0.0f, m2 = 0.0f, m3 = 0.0f;
    for (; i < n16; i += stride) {
        const float4v* p = ((const float4v*)src) + i * 4;
        float4v v0 = p[0], v1 = p[1], v2 = p[2], v3 = p[3];
        m0 = fmaxf(m0, fmaxf(fmaxf(fabsf(v0.x), fabsf(v0.y)), fmaxf(fabsf(v0.z), fabsf(v0.w))));
        m1 = fmaxf(m1, fmaxf(fmaxf(fabsf(v1.x), fabsf(v1.y)), fmaxf(fabsf(v1.z), fabsf(v1.w))));
        m2 = fmaxf(m2, fmaxf(fmaxf(fabsf(v2.x), fabsf(v2.y)), fmaxf(fabsf(v2.z), fabsf(v2.w))));
        m3 = fmaxf(m3, fmaxf(fmaxf(fabsf(v3.x), fabsf(v3.y)), fmaxf(fabsf(v3.z), fabsf(v3.w))));
    }
    float m = fmaxf(fmaxf(m0, m1), fmaxf(m2, m3));
    #pragma unroll
    for (int off = 32; off; off >>= 1) m = fmaxf(m, __shfl_xor(m, off, 64));
    if ((threadIdx.x & 63) == 0) atomicMax((unsigned int*)out, __float_as_uint(m));
}

// ---------------- fp32 -> int8 quantize: clip(rint(x/scale), lo, hi) ----------------
// 16 elements / thread / iter; n16 = n/16
__global__ void quant_kernel(const float* __restrict__ src, signed char* __restrict__ dst,
                             const float* __restrict__ stats, int slot,
                             float lo, float hi, long n16) {
    const float scale = stats[slot] / 127.0f;
    long i = (long)blockIdx.x * blockDim.x + threadIdx.x;
    long stride = (long)gridDim.x * blockDim.x;
    for (; i < n16; i += stride) {
        const float4v* s4 = ((const float4v*)src) + i * 4;
        float4v v0 = s4[0], v1 = s4[1], v2 = s4[2], v3 = s4[3];
        int32x4 outv;
        float4v vs[4] = {v0, v1, v2, v3};
        #pragma unroll
        for (int j = 0; j < 4; ++j) {
            float4v v = vs[j];
            int b0 = (int)fminf(fmaxf(rintf(v.x / scale), lo), hi);
            int b1 = (int)fminf(fmaxf(rintf(v.y / scale), lo), hi);
            int b2 = (int)fminf(fmaxf(rintf(v.z / scale), lo), hi);
            int b3 = (int)fminf(fmaxf(rintf(v.w / scale), lo), hi);
            outv[j] = (b0 & 0xff) | ((b1 & 0xff) << 8) | ((b2 & 0xff) << 16) | ((b3 & 0xff) << 24);
        }
        ((int32x4*)dst)[i] = outv;
    }
}

// ---------------- int8 GEMM: C[M,Ncols] = dequant(A[M,K] @ Bw[N,K]^T + bias) ----------------
// A row-major int8 (quantized activations), Bw row-major int8 (quantized weights, N x K).
// Epilogue: v = (acc + rint(bias/s)) * s ; optional ReLU + global running max (next act scale).
template <int BM, int BN, int FR, int FC, bool RELUMAX>
__global__ __launch_bounds__(256, 4)
void gemm_q8(const signed char* __restrict__ A, const signed char* __restrict__ Bw,
             const float* __restrict__ bias, float* __restrict__ stats,
             int a_slot, int w_slot, int h_slot,
             float* __restrict__ C, int K, int Ncols) {
    constexpr int BK = 64;                       // 64 int8 k-values per step (one x64 MFMA deep)
    constexpr int NWC = BN / (FC * 16);          // wave columns
    static_assert((BM / (FR * 16)) * (BN / (FC * 16)) == 4, "4 waves");
    constexpr int LDS_A = BM * BK;
    constexpr int LDS_TILE = (BM + BN) * BK;
    __shared__ __align__(16) signed char lds[2][LDS_TILE];

    const int tid  = threadIdx.x;
    const int wid  = tid >> 6;
    const int lane = tid & 63;
    const int wr   = wid / NWC;
    const int wc   = wid % NWC;

    const long brow = (long)blockIdx.y * BM;
    const long bcol = (long)blockIdx.x * BN;

    const signed char* Ab = A  + brow * K;
    const signed char* Bb = Bw + bcol * K;

    const int srow = tid >> 2;        // 0..63: row handled by this thread when staging
    const int scb  = (tid & 3) * 16;  // byte column (16B chunk)

    int32x4 zero = {0, 0, 0, 0};
    int32x4 acc[FR][FC];
    #pragma unroll
    for (int r = 0; r < FR; ++r)
        #pragma unroll
        for (int c = 0; c < FC; ++c) acc[r][c] = zero;

    auto stage = [&](int buf, int kt) {
        #pragma unroll
        for (int i = 0; i < BM / 64; ++i) {
            __builtin_amdgcn_global_load_lds(
                (const __attribute__((address_space(1))) void*)(Ab + (long)(srow + i * 64) * K + kt + scb),
                (__attribute__((address_space(3))) void*)(&lds[buf][(srow + i * 64) * BK + scb]),
                16, 0, 0);
        }
        #pragma unroll
        for (int i = 0; i < BN / 64; ++i) {
            __builtin_amdgcn_global_load_lds(
                (const __attribute__((address_space(1))) void*)(Bb + (long)(srow + i * 64) * K + kt + scb),
                (__attribute__((address_space(3))) void*)(&lds[buf][LDS_A + (srow + i * 64) * BK + scb]),
                16, 0, 0);
        }
    };

    const int nt = K / BK;
    stage(0, 0);
    __syncthreads();   // compiler drains vmcnt before barrier

    int cur = 0;
    for (int t = 0; t < nt; ++t) {
        if (t + 1 < nt) stage(cur ^ 1, (t + 1) * BK);

        const signed char* la = &lds[cur][0];
        const signed char* lb = &lds[cur][LDS_A];
        int32x4 af[FR], bf[FC];
        #pragma unroll
        for (int r = 0; r < FR; ++r)
            af[r] = *(const int32x4*)(la + (wr * (FR * 16) + r * 16 + (lane & 15)) * BK + (lane >> 4) * 16);
        #pragma unroll
        for (int c = 0; c < FC; ++c)
            bf[c] = *(const int32x4*)(lb + (wc * (FC * 16) + c * 16 + (lane & 15)) * BK + (lane >> 4) * 16);

        #pragma unroll
        for (int r = 0; r < FR; ++r)
            #pragma unroll
            for (int c = 0; c < FC; ++c)
                acc[r][c] = __builtin_amdgcn_mfma_i32_16x16x64_i8(af[r], bf[c], acc[r][c], 0, 0, 0);

        __syncthreads();
        cur ^= 1;
    }

    // epilogue: dequant + bias + (relu, running max)
    const float sa = stats[a_slot] / 127.0f;
    const float sw = stats[w_slot] / 127.0f;
    const float s  = sa * sw;
    float lmax = 0.0f;
    #pragma unroll
    for (int c = 0; c < FC; ++c) {
        const long col = bcol + wc * (FC * 16) + c * 16 + (lane & 15);
        const bool colok = (col < Ncols);
        float bint = 0.0f;
        if (colok) bint = rintf(bias[col] / s);
        #pragma unroll
        for (int r = 0; r < FR; ++r) {
            #pragma unroll
            for (int j = 0; j < 4; ++j) {
                const long row = brow + wr * (FR * 16) + r * 16 + (lane >> 4) * 4 + j;
                float v = ((float)acc[r][c][j] + bint) * s;
                if (RELUMAX) v = fmaxf(v, 0.0f);
                if (colok) C[row * Ncols + col] = v;
                if (RELUMAX) lmax = fmaxf(lmax, v);
            }
        }
    }
    if (RELUMAX) {
        #pragma unroll
        for (int off = 32; off; off >>= 1) lmax = fmaxf(lmax, __shfl_xor(lmax, off, 64));
        if (lane == 0) atomicMax((unsigned int*)&stats[h_slot], __float_as_uint(lmax));
    }
}

static inline long lminl(long a, long b) { return a < b ? a : b; }

extern "C" void kernel_launch(void* const* d_in, const int* in_sizes, int n_in,
                              void* d_out, int out_size, void* d_ws, size_t ws_size,
                              hipStream_t stream) {
    const float* x  = (const float*)d_in[0];
    const float* w1 = (const float*)d_in[1];
    const float* b1 = (const float*)d_in[2];
    const float* w2 = (const float*)d_in[3];
    const float* b2 = (const float*)d_in[4];
    const float* w3 = (const float*)d_in[5];
    const float* b3 = (const float*)d_in[6];
    float* out = (float*)d_out;

    constexpr int B = 512, DIN = 9216, DH = 4096, DOUT = 1000;

    // workspace carve-up
    char* ws = (char*)d_ws;
    float*       stats = (float*)ws;                       // 256 B
    signed char* xq    = (signed char*)(ws + 256);         // 512*9216
    signed char* w1q   = xq  + (size_t)B * DIN;            // 4096*9216
    signed char* w2q   = w1q + (size_t)DH * DIN;           // 4096*4096
    signed char* w3q   = w2q + (size_t)DH * DH;            // 1024*4096 (padded rows)
    signed char* h1q   = w3q + (size_t)1024 * DH;          // 512*4096
    signed char* h2q   = h1q + (size_t)B * DH;             // 512*4096
    float*       hbuf  = (float*)(h2q + (size_t)B * DH);   // 512*4096 fp32 (shared h1/h2)
    const size_t need  = 256 + (size_t)B*DIN + (size_t)DH*DIN + (size_t)DH*DH + (size_t)1024*DH
                       + 2*(size_t)B*DH + (size_t)B*DH*4;
    if (ws_size < need) return;  // avoid corrupting memory if workspace too small

    init_stats<<<1, 64, 0, stream>>>(stats);

    auto launch_maxabs = [&](const float* p, long n, int slot) {
        long n16 = n / 16;
        int blocks = (int)lminl((n16 + 255) / 256, 4096);
        maxabs_kernel<<<blocks, 256, 0, stream>>>(p, n16, stats + slot);
    };
    auto launch_quant = [&](const float* p, signed char* q, long n, int slot, float lo) {
        long n16 = n / 16;
        int blocks = (int)lminl((n16 + 255) / 256, 4096);
        quant_kernel<<<blocks, 256, 0, stream>>>(p, q, stats, slot, lo, 127.0f, n16);
    };

    // quantize inputs (maxabs then quant back-to-back for L3 reuse)
    launch_maxabs(x, (long)B * DIN, 0);
    launch_quant(x, xq, (long)B * DIN, 0, -128.0f);      // activations: lo = -N_LEVELS-1
    launch_maxabs(w1, (long)DH * DIN, 1);
    launch_quant(w1, w1q, (long)DH * DIN, 1, -127.0f);   // weights: lo = -N_LEVELS
    launch_maxabs(w2, (long)DH * DH, 2);
    launch_quant(w2, w2q, (long)DH * DH, 2, -127.0f);
    launch_maxabs(w3, (long)DOUT * DH, 3);
    launch_quant(w3, w3q, (long)DOUT * DH, 3, -127.0f);

    // fc1 + relu + running max -> hbuf ; then quantize h1
    gemm_q8<64, 128, 2, 4, true><<<dim3(DH / 128, B / 64), 256, 0, stream>>>(
        xq, w1q, b1, stats, 0, 1, 4, hbuf, DIN, DH);
    launch_quant(hbuf, h1q, (long)B * DH, 4, -128.0f);

    // fc2 + relu + running max -> hbuf ; then quantize h2
    gemm_q8<64, 128, 2, 4, true><<<dim3(DH / 128, B / 64), 256, 0, stream>>>(
        h1q, w2q, b2, stats, 4, 2, 5, hbuf, DH, DH);
    launch_quant(hbuf, h2q, (long)B * DH, 5, -128.0f);

    // fc3 (no relu), N=1000 with bounds check (w3q padded to 1024 rows)
    gemm_q8<64, 64, 2, 2, false><<<dim3(16, B / 64), 256, 0, stream>>>(
        h2q, w3q, b3, stats, 5, 3, 0, out, DH, DOUT);
}

// Round 3
// 542.973 us; speedup vs baseline: 1.6905x; 1.6905x over previous
//
#include <hip/hip_runtime.h>
#include <hip/hip_bf16.h>

typedef __attribute__((ext_vector_type(4))) int   int32x4;
typedef __attribute__((ext_vector_type(4))) float float4v;

// ---------------- stats layout (floats at ws+0) ----------------
// [0]=absmax_x [1]=absmax_w1 [2]=absmax_w2 [3]=absmax_w3 [4]=hmax1 [5]=hmax2

__global__ void init_stats(float* stats) {
    if (threadIdx.x < 64) stats[threadIdx.x] = 0.0f;
}

// ---------------- max|x| reduction ----------------
// Chunked: each block-iteration owns a contiguous 4096-float chunk (1024 float4).
// Thread does 4 fully-coalesced float4 loads (lane-contiguous, 4 independent chains).
// Block-level reduce -> ONE atomic per block (prev: per-wave atomics serialized at
// one address and dominated runtime).
__global__ void maxabs_kernel(const float* __restrict__ src, long nchunk, float* __restrict__ out) {
    const int tid  = threadIdx.x;
    const int lane = tid & 63;
    const int wid  = tid >> 6;
    __shared__ float red[4];
    float m0 = 0.0f, m1 = 0.0f, m2 = 0.0f, m3 = 0.0f;
    for (long c = blockIdx.x; c < nchunk; c += gridDim.x) {
        const float4v* p = (const float4v*)src + c * 1024 + tid;
        float4v v0 = p[0], v1 = p[256], v2 = p[512], v3 = p[768];
        m0 = fmaxf(m0, fmaxf(fmaxf(fabsf(v0.x), fabsf(v0.y)), fmaxf(fabsf(v0.z), fabsf(v0.w))));
        m1 = fmaxf(m1, fmaxf(fmaxf(fabsf(v1.x), fabsf(v1.y)), fmaxf(fabsf(v1.z), fabsf(v1.w))));
        m2 = fmaxf(m2, fmaxf(fmaxf(fabsf(v2.x), fabsf(v2.y)), fmaxf(fabsf(v2.z), fabsf(v2.w))));
        m3 = fmaxf(m3, fmaxf(fmaxf(fabsf(v3.x), fabsf(v3.y)), fmaxf(fabsf(v3.z), fabsf(v3.w))));
    }
    float m = fmaxf(fmaxf(m0, m1), fmaxf(m2, m3));
    #pragma unroll
    for (int off = 32; off; off >>= 1) m = fmaxf(m, __shfl_xor(m, off, 64));
    if (lane == 0) red[wid] = m;
    __syncthreads();
    if (tid == 0) {
        float r = fmaxf(fmaxf(red[0], red[1]), fmaxf(red[2], red[3]));
        atomicMax((unsigned int*)out, __float_as_uint(r));
    }
}

// ---------------- fp32 -> int8 quantize: clip(rint(x/scale), lo, hi) ----------------
// Same chunked/coalesced pattern: 4 coalesced float4 loads -> 4 coalesced dword stores.
__global__ void quant_kernel(const float* __restrict__ src, signed char* __restrict__ dst,
                             const float* __restrict__ stats, int slot,
                             float lo, float hi, long nchunk) {
    const float scale = stats[slot] / 127.0f;
    const int tid = threadIdx.x;
    for (long c = blockIdx.x; c < nchunk; c += gridDim.x) {
        const float4v* p = (const float4v*)src + c * 1024 + tid;
        int* d = (int*)dst + c * 1024 + tid;
        float4v v0 = p[0], v1 = p[256], v2 = p[512], v3 = p[768];
        float4v vs[4] = {v0, v1, v2, v3};
        int packed[4];
        #pragma unroll
        for (int j = 0; j < 4; ++j) {
            float4v v = vs[j];
            int b0 = (int)fminf(fmaxf(rintf(v.x / scale), lo), hi);
            int b1 = (int)fminf(fmaxf(rintf(v.y / scale), lo), hi);
            int b2 = (int)fminf(fmaxf(rintf(v.z / scale), lo), hi);
            int b3 = (int)fminf(fmaxf(rintf(v.w / scale), lo), hi);
            packed[j] = (b0 & 0xff) | ((b1 & 0xff) << 8) | ((b2 & 0xff) << 16) | ((b3 & 0xff) << 24);
        }
        d[0]   = packed[0];
        d[256] = packed[1];
        d[512] = packed[2];
        d[768] = packed[3];
    }
}

// ---------------- int8 GEMM: C[M,Ncols] = dequant(A[M,K] @ Bw[N,K]^T + bias) ----------------
// A row-major int8 (quantized activations), Bw row-major int8 (quantized weights, N x K).
// Epilogue: v = (acc + rint(bias/s)) * s ; optional ReLU + global running max (next act scale).
template <int BM, int BN, int FR, int FC, bool RELUMAX>
__global__ __launch_bounds__(256, 4)
void gemm_q8(const signed char* __restrict__ A, const signed char* __restrict__ Bw,
             const float* __restrict__ bias, float* __restrict__ stats,
             int a_slot, int w_slot, int h_slot,
             float* __restrict__ C, int K, int Ncols) {
    constexpr int BK = 64;                       // 64 int8 k-values per step (one x64 MFMA deep)
    constexpr int NWC = BN / (FC * 16);          // wave columns
    static_assert((BM / (FR * 16)) * (BN / (FC * 16)) == 4, "4 waves");
    constexpr int LDS_A = BM * BK;
    constexpr int LDS_TILE = (BM + BN) * BK;
    __shared__ __align__(16) signed char lds[2][LDS_TILE];

    const int tid  = threadIdx.x;
    const int wid  = tid >> 6;
    const int lane = tid & 63;
    const int wr   = wid / NWC;
    const int wc   = wid % NWC;

    const long brow = (long)blockIdx.y * BM;
    const long bcol = (long)blockIdx.x * BN;

    const signed char* Ab = A  + brow * K;
    const signed char* Bb = Bw + bcol * K;

    const int srow = tid >> 2;        // 0..63: row handled by this thread when staging
    const int scb  = (tid & 3) * 16;  // byte column (16B chunk)

    int32x4 zero = {0, 0, 0, 0};
    int32x4 acc[FR][FC];
    #pragma unroll
    for (int r = 0; r < FR; ++r)
        #pragma unroll
        for (int c = 0; c < FC; ++c) acc[r][c] = zero;

    auto stage = [&](int buf, int kt) {
        #pragma unroll
        for (int i = 0; i < BM / 64; ++i) {
            __builtin_amdgcn_global_load_lds(
                (const __attribute__((address_space(1))) void*)(Ab + (long)(srow + i * 64) * K + kt + scb),
                (__attribute__((address_space(3))) void*)(&lds[buf][(srow + i * 64) * BK + scb]),
                16, 0, 0);
        }
        #pragma unroll
        for (int i = 0; i < BN / 64; ++i) {
            __builtin_amdgcn_global_load_lds(
                (const __attribute__((address_space(1))) void*)(Bb + (long)(srow + i * 64) * K + kt + scb),
                (__attribute__((address_space(3))) void*)(&lds[buf][LDS_A + (srow + i * 64) * BK + scb]),
                16, 0, 0);
        }
    };

    const int nt = K / BK;
    stage(0, 0);
    __syncthreads();   // compiler drains vmcnt before barrier

    int cur = 0;
    for (int t = 0; t < nt; ++t) {
        if (t + 1 < nt) stage(cur ^ 1, (t + 1) * BK);

        const signed char* la = &lds[cur][0];
        const signed char* lb = &lds[cur][LDS_A];
        int32x4 af[FR], bf[FC];
        #pragma unroll
        for (int r = 0; r < FR; ++r)
            af[r] = *(const int32x4*)(la + (wr * (FR * 16) + r * 16 + (lane & 15)) * BK + (lane >> 4) * 16);
        #pragma unroll
        for (int c = 0; c < FC; ++c)
            bf[c] = *(const int32x4*)(lb + (wc * (FC * 16) + c * 16 + (lane & 15)) * BK + (lane >> 4) * 16);

        #pragma unroll
        for (int r = 0; r < FR; ++r)
            #pragma unroll
            for (int c = 0; c < FC; ++c)
                acc[r][c] = __builtin_amdgcn_mfma_i32_16x16x64_i8(af[r], bf[c], acc[r][c], 0, 0, 0);

        __syncthreads();
        cur ^= 1;
    }

    // epilogue: dequant + bias + (relu, running max)
    const float sa = stats[a_slot] / 127.0f;
    const float sw = stats[w_slot] / 127.0f;
    const float s  = sa * sw;
    float lmax = 0.0f;
    #pragma unroll
    for (int c = 0; c < FC; ++c) {
        const long col = bcol + wc * (FC * 16) + c * 16 + (lane & 15);
        const bool colok = (col < Ncols);
        float bint = 0.0f;
        if (colok) bint = rintf(bias[col] / s);
        #pragma unroll
        for (int r = 0; r < FR; ++r) {
            #pragma unroll
            for (int j = 0; j < 4; ++j) {
                const long row = brow + wr * (FR * 16) + r * 16 + (lane >> 4) * 4 + j;
                float v = ((float)acc[r][c][j] + bint) * s;
                if (RELUMAX) v = fmaxf(v, 0.0f);
                if (colok) C[row * Ncols + col] = v;
                if (RELUMAX) lmax = fmaxf(lmax, v);
            }
        }
    }
    if (RELUMAX) {
        __shared__ float red[4];
        #pragma unroll
        for (int off = 32; off; off >>= 1) lmax = fmaxf(lmax, __shfl_xor(lmax, off, 64));
        if (lane == 0) red[wid] = lmax;
        __syncthreads();
        if (tid == 0) {
            float r = fmaxf(fmaxf(red[0], red[1]), fmaxf(red[2], red[3]));
            atomicMax((unsigned int*)&stats[h_slot], __float_as_uint(r));
        }
    }
}

static inline long lminl(long a, long b) { return a < b ? a : b; }

extern "C" void kernel_launch(void* const* d_in, const int* in_sizes, int n_in,
                              void* d_out, int out_size, void* d_ws, size_t ws_size,
                              hipStream_t stream) {
    const float* x  = (const float*)d_in[0];
    const float* w1 = (const float*)d_in[1];
    const float* b1 = (const float*)d_in[2];
    const float* w2 = (const float*)d_in[3];
    const float* b2 = (const float*)d_in[4];
    const float* w3 = (const float*)d_in[5];
    const float* b3 = (const float*)d_in[6];
    float* out = (float*)d_out;

    constexpr int B = 512, DIN = 9216, DH = 4096, DOUT = 1000;

    // workspace carve-up
    char* ws = (char*)d_ws;
    float*       stats = (float*)ws;                       // 256 B
    signed char* xq    = (signed char*)(ws + 256);         // 512*9216
    signed char* w1q   = xq  + (size_t)B * DIN;            // 4096*9216
    signed char* w2q   = w1q + (size_t)DH * DIN;           // 4096*4096
    signed char* w3q   = w2q + (size_t)DH * DH;            // 1024*4096 (padded rows)
    signed char* h1q   = w3q + (size_t)1024 * DH;          // 512*4096
    signed char* h2q   = h1q + (size_t)B * DH;             // 512*4096
    float*       hbuf  = (float*)(h2q + (size_t)B * DH);   // 512*4096 fp32 (shared h1/h2)
    const size_t need  = 256 + (size_t)B*DIN + (size_t)DH*DIN + (size_t)DH*DH + (size_t)1024*DH
                       + 2*(size_t)B*DH + (size_t)B*DH*4;
    if (ws_size < need) return;  // avoid corrupting memory if workspace too small

    init_stats<<<1, 64, 0, stream>>>(stats);

    auto launch_maxabs = [&](const float* p, long n, int slot) {
        long nchunk = n / 4096;                 // all sizes are multiples of 4096 floats
        int blocks = (int)lminl(nchunk, 2048);
        maxabs_kernel<<<blocks, 256, 0, stream>>>(p, nchunk, stats + slot);
    };
    auto launch_quant = [&](const float* p, signed char* q, long n, int slot, float lo) {
        long nchunk = n / 4096;
        int blocks = (int)lminl(nchunk, 2048);
        quant_kernel<<<blocks, 256, 0, stream>>>(p, q, stats, slot, lo, 127.0f, nchunk);
    };

    // quantize inputs (maxabs then quant back-to-back for L3 reuse)
    launch_maxabs(x, (long)B * DIN, 0);
    launch_quant(x, xq, (long)B * DIN, 0, -128.0f);      // activations: lo = -N_LEVELS-1
    launch_maxabs(w1, (long)DH * DIN, 1);
    launch_quant(w1, w1q, (long)DH * DIN, 1, -127.0f);   // weights: lo = -N_LEVELS
    launch_maxabs(w2, (long)DH * DH, 2);
    launch_quant(w2, w2q, (long)DH * DH, 2, -127.0f);
    launch_maxabs(w3, (long)DOUT * DH, 3);
    launch_quant(w3, w3q, (long)DOUT * DH, 3, -127.0f);

    // fc1 + relu + running max -> hbuf ; then quantize h1
    gemm_q8<64, 128, 2, 4, true><<<dim3(DH / 128, B / 64), 256, 0, stream>>>(
        xq, w1q, b1, stats, 0, 1, 4, hbuf, DIN, DH);
    launch_quant(hbuf, h1q, (long)B * DH, 4, -128.0f);

    // fc2 + relu + running max -> hbuf ; then quantize h2
    gemm_q8<64, 128, 2, 4, true><<<dim3(DH / 128, B / 64), 256, 0, stream>>>(
        h1q, w2q, b2, stats, 4, 2, 5, hbuf, DH, DH);
    launch_quant(hbuf, h2q, (long)B * DH, 5, -128.0f);

    // fc3 (no relu), N=1000 with bounds check (w3q padded to 1024 rows)
    gemm_q8<64, 64, 2, 2, false><<<dim3(16, B / 64), 256, 0, stream>>>(
        h2q, w3q, b3, stats, 5, 3, 0, out, DH, DOUT);
}